// Round 2
// baseline (38863.885 us; speedup 1.0000x reference)
//
#include <hip/hip_runtime.h>
#include <hip/hip_bf16.h>
#include <math.h>

// Problem constants
#define BB 64
#define SS 512
#define HH 512
#define AA 512
#define NC 4
#define VV 1000
#define ED 128
#define NF 6
#define NL 2

// Chunking: 8 row-chunks of 4096 rows; 8 batch-groups of 8; 8 step-chunks of 64
#define GROUPB 8     // batches per attention group
#define NGROUP 8
#define CHSTEP 64    // GRU timesteps per gi chunk
#define NCHUNK 8

// ---------------------------------------------------------------------------
// Zero-init kernel (avoid hipMemsetAsync entirely)
// ---------------------------------------------------------------------------
__global__ __launch_bounds__(256) void zero_kernel(float* __restrict__ p, int n) {
    int i = blockIdx.x * 256 + threadIdx.x;
    if (i < n) p[i] = 0.f;
}

// ---------------------------------------------------------------------------
// Positional encoding: pe[s][2j] = sin(s * 10000^(-2j/512)), pe[s][2j+1] = cos
// ---------------------------------------------------------------------------
__global__ __launch_bounds__(256) void pe_kernel(float* __restrict__ pe) {
    int s = blockIdx.x;          // 0..511
    int j = threadIdx.x;         // 0..255 (pair index)
    float ang = (float)s * powf(10000.0f, -(2.0f * (float)j) / 512.0f);
    pe[s * 512 + 2 * j]     = sinf(ang);
    pe[s * 512 + 2 * j + 1] = cosf(ang);
}

// ---------------------------------------------------------------------------
// Build one 4096-row chunk of xcat:
//   xcat_c[r,0:512]    = embedding gather (4 features x 128)
//   xcat_c[r,512:1024] = cont_x @ W_cont + b_cont
// Global row = gbase + blockIdx.x.
// ---------------------------------------------------------------------------
__global__ __launch_bounds__(256) void embed_kernel(
    const int* __restrict__ cate, const float* __restrict__ cont,
    const float* __restrict__ emb, const float* __restrict__ Wc,
    const float* __restrict__ bc, float* __restrict__ xcat_c, int gbase)
{
    long bs = (long)gbase + blockIdx.x;   // global row
    long r  = blockIdx.x;                 // local row
    __shared__ float cf[NF];
    if (threadIdx.x < NF) cf[threadIdx.x] = cont[bs * NF + threadIdx.x];
    __syncthreads();
    for (int h = threadIdx.x; h < 1024; h += 256) {
        float v;
        if (h < 512) {
            int c = h >> 7, e = h & 127;
            int idx = cate[bs * NC + c];
            v = emb[((long)c * VV + idx) * ED + e];
        } else {
            int hh = h - 512;
            v = bc[hh];
#pragma unroll
            for (int f = 0; f < NF; f++) v += cf[f] * Wc[f * 512 + hh];
        }
        xcat_c[r * 1024 + h] = v;
    }
}

// ---------------------------------------------------------------------------
// Generic fp32 tiled GEMM: C = alpha * A @ B (+bias) (+pe)
// A: [M,K] row-major (lda). B: [K,N] (ldb) or, if transB, [N,K] (ldb).
// Batched via grid.z with strides. Tile 64x64x16, 256 threads, 4x4 micro-tile.
// All M,N multiples of 64; K multiple of 16 (true for every call here).
// pe != nullptr: adds pe[(m0_global+m)&511][n] (requires N==512).
// ---------------------------------------------------------------------------
#define TM 64
#define TN 64
#define TK 16
__global__ __launch_bounds__(256) void gemm_f32(
    const float* __restrict__ A, const float* __restrict__ Bm, float* __restrict__ C,
    int M, int N, int K, int lda, int ldb, int ldc,
    long sA, long sB, long sC,
    const float* __restrict__ bias, const float* __restrict__ pe,
    float alpha, int transB)
{
    A += (long)blockIdx.z * sA;
    Bm += (long)blockIdx.z * sB;
    C += (long)blockIdx.z * sC;

    __shared__ float As[TK][TM + 4];
    __shared__ float Bs[TK][TN + 4];

    int tid = threadIdx.x;
    int tx = tid & 15, ty = tid >> 4;
    int m0 = blockIdx.y * TM, n0 = blockIdx.x * TN;

    float acc[4][4] = {};

    for (int k0 = 0; k0 < K; k0 += TK) {
        for (int idx = tid; idx < TM * TK; idx += 256) {
            int m = idx >> 4, kk = idx & 15;
            As[kk][m] = A[(long)(m0 + m) * lda + k0 + kk];
        }
        if (transB) {
            for (int idx = tid; idx < TN * TK; idx += 256) {
                int n = idx >> 4, kk = idx & 15;
                Bs[kk][n] = Bm[(long)(n0 + n) * ldb + k0 + kk];
            }
        } else {
            for (int idx = tid; idx < TN * TK; idx += 256) {
                int kk = idx >> 6, n = idx & 63;
                Bs[kk][n] = Bm[(long)(k0 + kk) * ldb + n0 + n];
            }
        }
        __syncthreads();
#pragma unroll
        for (int kk = 0; kk < TK; kk++) {
            float a[4], b[4];
#pragma unroll
            for (int i = 0; i < 4; i++) a[i] = As[kk][ty * 4 + i];
#pragma unroll
            for (int j = 0; j < 4; j++) b[j] = Bs[kk][tx * 4 + j];
#pragma unroll
            for (int i = 0; i < 4; i++)
#pragma unroll
                for (int j = 0; j < 4; j++) acc[i][j] += a[i] * b[j];
        }
        __syncthreads();
    }

#pragma unroll
    for (int i = 0; i < 4; i++) {
        int m = m0 + ty * 4 + i;
#pragma unroll
        for (int j = 0; j < 4; j++) {
            int n = n0 + tx * 4 + j;
            float v = acc[i][j] * alpha;
            if (bias) v += bias[n];
            if (pe)   v += pe[(long)(m & 511) * 512 + n];   // rows chunk-aligned to 512
            C[(long)m * ldc + n] = v;
        }
    }
}

// ---------------------------------------------------------------------------
// Softmax over the QUERY axis (axis=1): per (batch-in-group, k) column.
// sc: [GROUPB, 512, 512]
// ---------------------------------------------------------------------------
__global__ __launch_bounds__(64) void softmax_q(float* __restrict__ sc) {
    int b = blockIdx.x;                          // 0..GROUPB-1
    int k = blockIdx.y * 64 + threadIdx.x;       // 0..511
    float* p = sc + (long)b * SS * SS + k;
    float m = -1e30f;
    for (int q = 0; q < SS; q++) m = fmaxf(m, p[(long)q * SS]);
    float sum = 0.f;
    for (int q = 0; q < SS; q++) sum += expf(p[(long)q * SS] - m);
    float inv = 1.f / sum;
    for (int q = 0; q < SS; q++) {
        float v = expf(p[(long)q * SS] - m) * inv;
        p[(long)q * SS] = v;
    }
}

// ---------------------------------------------------------------------------
// Transpose one group's z [GROUPB,512,512] into zp [S, B, A] at batch bbase.
// ---------------------------------------------------------------------------
__global__ __launch_bounds__(256) void transpose_group(
    const float* __restrict__ zg, float* __restrict__ zp, int bbase)
{
    long idx = (long)blockIdx.x * 256 + threadIdx.x;   // < GROUPB*512*512
    int d = (int)(idx & 511);
    int s = (int)((idx >> 9) & 511);
    int bb = (int)(idx >> 18);
    zp[(((long)s * BB + bbase + bb) << 9) + d] = zg[idx];
}

// ---------------------------------------------------------------------------
// One GRU time step: h_new = GRU(gi_s (precomputed x@Wi^T+bi), h_prev)
// ---------------------------------------------------------------------------
__global__ __launch_bounds__(128) void gru_step(
    const float* __restrict__ gi_s,   // [64][1536] for this timestep (includes bi)
    const float* __restrict__ hprev,  // [64][512]
    const float* __restrict__ Wh_l,   // [1536][512] row-major
    const float* __restrict__ bh_l,   // [1536]
    float* __restrict__ hout)         // [64][512]
{
    __shared__ float hs[16][516];
    int bt = blockIdx.x >> 6;         // 0..3  (batch tile of 16)
    int ut = blockIdx.x & 63;         // 0..63 (unit tile of 8)
    int tid = threadIdx.x;

    for (int idx = tid; idx < 16 * 512; idx += 128) {
        int bl = idx >> 9, k = idx & 511;
        hs[bl][k] = hprev[(long)(bt * 16 + bl) * 512 + k];
    }
    __syncthreads();

    int bl = tid >> 3, ul = tid & 7;
    int b = bt * 16 + bl;
    int u = ut * 8 + ul;

    const float4* wr = (const float4*)(Wh_l + (long)u * 512);
    const float4* wz = (const float4*)(Wh_l + (long)(512 + u) * 512);
    const float4* wn = (const float4*)(Wh_l + (long)(1024 + u) * 512);
    const float4* hv = (const float4*)(&hs[bl][0]);

    float ar = 0.f, az = 0.f, an = 0.f;
#pragma unroll 8
    for (int k4 = 0; k4 < 128; k4++) {
        float4 h4 = hv[k4];
        float4 r4 = wr[k4];
        float4 z4 = wz[k4];
        float4 n4 = wn[k4];
        ar += r4.x * h4.x + r4.y * h4.y + r4.z * h4.z + r4.w * h4.w;
        az += z4.x * h4.x + z4.y * h4.y + z4.z * h4.z + z4.w * h4.w;
        an += n4.x * h4.x + n4.y * h4.y + n4.z * h4.z + n4.w * h4.w;
    }

    float ir  = gi_s[(long)b * 1536 + u];
    float iz  = gi_s[(long)b * 1536 + 512 + u];
    float inn = gi_s[(long)b * 1536 + 1024 + u];
    float hr = ar + bh_l[u];
    float hz = az + bh_l[512 + u];
    float hn = an + bh_l[1024 + u];
    float r  = 1.f / (1.f + expf(-(ir + hr)));
    float zg = 1.f / (1.f + expf(-(iz + hz)));
    float n  = tanhf(inn + r * hn);
    float hp = hs[bl][u];
    hout[(long)b * 512 + u] = (1.f - zg) * n + zg * hp;
}

// ---------------------------------------------------------------------------
// Final: out[b,s] = sigmoid( h2seq[s,b,:] . W_fin + b_fin ) — one wave per (s,b)
// ---------------------------------------------------------------------------
__global__ __launch_bounds__(256) void final_kernel(
    const float* __restrict__ h2, const float* __restrict__ Wf,
    const float* __restrict__ bf, float* __restrict__ out)
{
    int w = blockIdx.x * 4 + (threadIdx.x >> 6);  // wave id = s*64+b, < 32768
    int lane = threadIdx.x & 63;
    const float* row = h2 + (long)w * 512;
    float sum = 0.f;
#pragma unroll
    for (int j = 0; j < 8; j++) sum += row[j * 64 + lane] * Wf[j * 64 + lane];
#pragma unroll
    for (int off = 32; off > 0; off >>= 1) sum += __shfl_down(sum, off, 64);
    if (lane == 0) {
        int s = w >> 6, b = w & 63;
        out[(long)b * SS + s] = 1.f / (1.f + expf(-(sum + bf[0])));
    }
}

// ---------------------------------------------------------------------------
// Launcher — total workspace 52,723,712 floats = 201 MiB
// ---------------------------------------------------------------------------
extern "C" void kernel_launch(void* const* d_in, const int* in_sizes, int n_in,
                              void* d_out, int out_size, void* d_ws, size_t ws_size,
                              hipStream_t stream) {
    const int*   cate  = (const int*)  d_in[0];
    const float* cont  = (const float*)d_in[1];
    const float* emb   = (const float*)d_in[4];
    const float* Wc    = (const float*)d_in[5];
    const float* bc    = (const float*)d_in[6];
    const float* Wcomb = (const float*)d_in[7];
    const float* bcomb = (const float*)d_in[8];
    const float* Wq    = (const float*)d_in[9];
    const float* Wk    = (const float*)d_in[10];
    const float* Wv    = (const float*)d_in[11];
    const float* Wi    = (const float*)d_in[12];
    const float* Wh    = (const float*)d_in[13];
    const float* bi    = (const float*)d_in[14];
    const float* bh    = (const float*)d_in[15];
    const float* Wf    = (const float*)d_in[16];
    const float* bf    = (const float*)d_in[17];
    float* out = (float*)d_out;
    float* ws  = (float*)d_ws;

    // Workspace layout (float offsets)
    float* x     = ws;                      // [32768,512] -> later h1seq [S,B,512]
    float* h1seq = ws;
    float* zp    = ws + 16777216;           // [S,B,512]   -> later h2seq
    float* h2seq = ws + 16777216;
    float* Qg    = ws + 33554432;           // [8,512,512] -> later zg
    float* zg    = ws + 33554432;
    float* Kg    = ws + 35651584;           // [8,512,512]
    float* Vg    = ws + 37748736;           // [8,512,512]
    float* Sg    = ws + 39845888;           // [8,512,512]
    float* xc    = ws + 41943040;           // [4096,1024]
    float* gi    = ws + 46137344;           // [4096,1536] (64 steps x 64 b)
    float* pe    = ws + 52428800;           // [512,512]
    float* h0    = ws + 52690944;           // [64,512]

    zero_kernel<<<128, 256, 0, stream>>>(h0, 64 * 512);
    pe_kernel<<<512, 256, 0, stream>>>(pe);

    // Phase 1: x = (embed ++ cont-proj) @ W_comb + b_comb + pe, in 8 row-chunks
    for (int g = 0; g < 8; g++) {
        embed_kernel<<<4096, 256, 0, stream>>>(cate, cont, emb, Wc, bc, xc, g * 4096);
        dim3 gr(512 / TN, 4096 / TM, 1);
        gemm_f32<<<gr, 256, 0, stream>>>(xc, Wcomb, x + (long)g * 4096 * 512,
                                         4096, 512, 1024, 1024, 512, 512,
                                         0, 0, 0, bcomb, pe, 1.f, 0);
    }

    // Phase 2: attention per batch-group of 8
    for (int g = 0; g < NGROUP; g++) {
        const float* xg = x + (long)g * GROUPB * 512 * 512;
        dim3 gq(512 / TN, (GROUPB * 512) / TM, 1);
        gemm_f32<<<gq, 256, 0, stream>>>(xg, Wq, Qg, GROUPB * 512, 512, 512,
                                         512, 512, 512, 0, 0, 0, nullptr, nullptr, 1.f, 0);
        gemm_f32<<<gq, 256, 0, stream>>>(xg, Wk, Kg, GROUPB * 512, 512, 512,
                                         512, 512, 512, 0, 0, 0, nullptr, nullptr, 1.f, 0);
        gemm_f32<<<gq, 256, 0, stream>>>(xg, Wv, Vg, GROUPB * 512, 512, 512,
                                         512, 512, 512, 0, 0, 0, nullptr, nullptr, 1.f, 0);
        // Sg[bb] = Qg[bb] @ Kg[bb]^T / sqrt(A)
        dim3 gs(512 / TN, 512 / TM, GROUPB);
        gemm_f32<<<gs, 256, 0, stream>>>(Qg, Kg, Sg, 512, 512, 512, 512, 512, 512,
                                         262144, 262144, 262144, nullptr, nullptr,
                                         0.04419417382415922f, 1);
        softmax_q<<<dim3(GROUPB, 8), 64, 0, stream>>>(Sg);
        // zg[bb] = Sg[bb] @ Vg[bb]   (overwrites Qg slot)
        gemm_f32<<<gs, 256, 0, stream>>>(Sg, Vg, zg, 512, 512, 512, 512, 512, 512,
                                         262144, 262144, 262144, nullptr, nullptr, 1.f, 0);
        transpose_group<<<8192, 256, 0, stream>>>(zg, zp, g * GROUPB);
    }

    // Phase 3: 2 GRU layers; gi computed in chunks of 64 timesteps
    for (int l = 0; l < NL; l++) {
        const float* seq_in  = (l == 0) ? zp : h1seq;
        float* seq_out       = (l == 0) ? h1seq : h2seq;
        const float* Wi_l = Wi + (long)l * 1536 * 512;
        const float* Wh_l = Wh + (long)l * 1536 * 512;
        const float* bi_l = bi + (long)l * 1536;
        const float* bh_l = bh + (long)l * 1536;
        for (int c = 0; c < NCHUNK; c++) {
            // gi = seq_in[rows c*4096 .. +4096] @ Wi_l^T + bi_l
            dim3 gg(1536 / TN, 4096 / TM, 1);
            gemm_f32<<<gg, 256, 0, stream>>>(seq_in + (long)c * 4096 * 512, Wi_l, gi,
                                             4096, 1536, 512, 512, 512, 1536,
                                             0, 0, 0, bi_l, nullptr, 1.f, 1);
            for (int sl = 0; sl < CHSTEP; sl++) {
                int s = c * CHSTEP + sl;
                const float* hp = (s == 0) ? h0 : (seq_out + (long)(s - 1) * BB * 512);
                gru_step<<<256, 128, 0, stream>>>(gi + (long)sl * BB * 1536, hp,
                                                  Wh_l, bh_l,
                                                  seq_out + (long)s * BB * 512);
            }
        }
    }

    // Final projection + sigmoid
    final_kernel<<<32768 / 4, 256, 0, stream>>>(h2seq, Wf, bf, out);
}